// Round 12
// baseline (455.161 us; speedup 1.0000x reference)
//
#include <hip/hip_runtime.h>
#include <hip/hip_bf16.h>

typedef unsigned short u16;
typedef __attribute__((ext_vector_type(8))) short bf16x8;
typedef __attribute__((ext_vector_type(4))) float f32x4;

#define MFMA16(a, b, c) __builtin_amdgcn_mfma_f32_16x16x32_bf16(a, b, c, 0, 0, 0)

__device__ __forceinline__ u16 f2b(float f) {
  union { float f; unsigned u; } x; x.f = f;
  return (u16)((x.u + 0x7fffu + ((x.u >> 16) & 1u)) >> 16);
}

__device__ __forceinline__ void gload_lds16(const void* g, void* l) {
  __builtin_amdgcn_global_load_lds(
      (const __attribute__((address_space(1))) void*)g,
      (__attribute__((address_space(3))) void*)l, 16, 0, 0);
}

// linear frag-block stage: NCH chunks of 512 u16 (64 lanes x 16B), src contiguous
template <int NCH>
__device__ __forceinline__ void stage_frags(const u16* __restrict__ src,
                                            u16* dst, int wave, int lane) {
#pragma unroll
  for (int it = 0; it < NCH / 4; ++it) {
    int chunk = it * 4 + wave;
    gload_lds16(src + ((size_t)chunk * 64 + lane) * 8, dst + chunk * 512);
  }
}

// stage 64 rows x 192 cols bf16 -> LDS, chunk XOR-swizzled by row&7 (proj A).
__device__ __forceinline__ void stage_64x192(const u16* __restrict__ src,
                                             int stride, u16* dst, int wave,
                                             int lane) {
#pragma unroll
  for (int it = 0; it < 6; ++it) {
    int id = (it * 4 + wave) * 64 + lane;
    int row = id / 24, ph = id - row * 24;
    int lch = (ph & 24) | ((ph ^ (row & 7)) & 7);
    gload_lds16(src + (size_t)row * stride + lch * 8,
                dst + (it * 4 + wave) * 512);
  }
}

// ---------------- weight fp32 -> bf16 MFMA-fragment order ------------------
__global__ __launch_bounds__(256) void pack_kernel(const float* __restrict__ W,
                                                   u16* __restrict__ F, int NT,
                                                   int KS, int K, int kmajor) {
  int f = blockIdx.x * 256 + threadIdx.x;
  if (f >= NT * KS * 64) return;
  int l = f & 63, rest = f >> 6;
  int ks, ct;
  if (kmajor) { ct = rest % NT; ks = rest / NT; }
  else        { ks = rest % KS; ct = rest / KS; }
  int row = ct * 16 + (l & 15);
  int col = ks * 32 + (l >> 4) * 8;
  const float* s = W + (size_t)row * K + col;
  u16* d = F + (size_t)f * 8;
#pragma unroll
  for (int i = 0; i < 8; ++i) d[i] = f2b(s[i]);
}

// fc2 pack with pi-permuted k within each 32-h chunk (matches lane-local pf):
// pi(g,i) = 4g+i (i<4), 16+4g+(i-4) (i>=4). frag id = hs*12 + ct.
__global__ __launch_bounds__(256) void pack2_kernel(const float* __restrict__ W,
                                                    u16* __restrict__ F) {
  int f = blockIdx.x * 256 + threadIdx.x;
  if (f >= 24 * 12 * 64) return;
  int l = f & 63, rest = f >> 6;
  int ct = rest % 12, hs = rest / 12;
  int row = ct * 16 + (l & 15);
  int g = l >> 4;
  u16* d = F + (size_t)f * 8;
#pragma unroll
  for (int i = 0; i < 8; ++i) {
    int h = hs * 32 + (i < 4 ? 4 * g + i : 16 + 4 * g + (i - 4));
    d[i] = f2b(W[(size_t)row * 768 + h]);
  }
}

// ---------------- fused LN1 + shift/window + QKV GEMM ----------------------
__global__ __launch_bounds__(256, 3) void qkv_fused(
    const float* __restrict__ x, const float* __restrict__ n1w,
    const float* __restrict__ n1b, const u16* __restrict__ wf,
    const float* __restrict__ qkvb_, u16* __restrict__ qb,
    u16* __restrict__ kb, u16* __restrict__ vb, int tok0) {
  __shared__ __align__(16) u16 lds[24576];  // 48 KB
  u16* sA = lds;            // 12288 u16, overlays b0
  u16* b0 = lds;            // 24 frags (12288 u16)
  u16* b1 = lds + 12288;
  int tid = threadIdx.x, wave = tid >> 6, lane = tid & 63;
  int g = lane >> 4, c = lane & 15, wr = wave * 16;
  int m0 = blockIdx.x * 64;
  // --- LN1: wave owns 16 rows; write sA swizzled ---
  {
    float vals[12][4];
    int srcrow[4];
#pragma unroll
    for (int reg = 0; reg < 4; ++reg) {
      int rg = tok0 + m0 + wr + 4 * g + reg;
      int win = rg / 49, n = rg - win * 49;
      int bb = win >> 6, wi = win & 63, wh = wi >> 3, ww = wi & 7;
      int rr = n / 7, cc = n - rr * 7;
      int hs = wh * 7 + rr + 3; if (hs >= 56) hs -= 56;
      int ws = ww * 7 + cc + 3; if (ws >= 56) ws -= 56;
      srcrow[reg] = bb * 3136 + hs * 56 + ws;
    }
#pragma unroll
    for (int nt = 0; nt < 12; ++nt)
#pragma unroll
      for (int reg = 0; reg < 4; ++reg)
        vals[nt][reg] = x[(size_t)srcrow[reg] * 192 + nt * 16 + c];
#pragma unroll
    for (int reg = 0; reg < 4; ++reg) {
      float s = 0.f;
#pragma unroll
      for (int nt = 0; nt < 12; ++nt) s += vals[nt][reg];
      s += __shfl_xor(s, 1, 64); s += __shfl_xor(s, 2, 64);
      s += __shfl_xor(s, 4, 64); s += __shfl_xor(s, 8, 64);
      float m = s * (1.f / 192.f), q = 0.f;
#pragma unroll
      for (int nt = 0; nt < 12; ++nt) { float d = vals[nt][reg] - m; q += d * d; }
      q += __shfl_xor(q, 1, 64); q += __shfl_xor(q, 2, 64);
      q += __shfl_xor(q, 4, 64); q += __shfl_xor(q, 8, 64);
      float rs = rsqrtf(q * (1.f / 192.f) + 1e-5f);
#pragma unroll
      for (int nt = 0; nt < 12; ++nt) vals[nt][reg] = (vals[nt][reg] - m) * rs;
    }
#pragma unroll
    for (int nt = 0; nt < 12; ++nt) {
      float wv = n1w[nt * 16 + c], bv = n1b[nt * 16 + c];
#pragma unroll
      for (int reg = 0; reg < 4; ++reg) {
        int r = wr + 4 * g + reg;
        int ch = nt * 2 + (c >> 3);
        int ph = (ch & 24) | ((ch ^ (r & 7)) & 7);
        sA[r * 192 + ph * 8 + (c & 7)] = f2b(vals[nt][reg] * wv + bv);
      }
    }
  }
  __syncthreads();
  int mw = wave >> 1, nw = wave & 1;
  bf16x8 afr[2][6];
#pragma unroll
  for (int rt = 0; rt < 2; ++rt) {
    int ar = mw * 32 + rt * 16 + c;
#pragma unroll
    for (int ks = 0; ks < 6; ++ks) {
      int ch = ks * 4 + g;
      int ph = (ch & 24) | ((ch ^ (ar & 7)) & 7);
      afr[rt][ks] = *(const bf16x8*)(sA + ar * 192 + ph * 8);
    }
  }
  __syncthreads();  // sA dead -> b0 region reusable
  stage_frags<24>(wf, b0, wave, lane);
  int win0 = tok0 / 49;
  __syncthreads();  // b0 staged (barrier drains vmcnt)
  for (int j = 0; j < 9; ++j) {
    const u16* cb = (j & 1) ? b1 : b0;
    if (j < 8)
      stage_frags<24>(wf + (size_t)(j + 1) * 24 * 512, (j & 1) ? b0 : b1, wave,
                      lane);
    f32x4 S[2][2] = {{{0,0,0,0},{0,0,0,0}},{{0,0,0,0},{0,0,0,0}}};
#pragma unroll
    for (int nt = 0; nt < 2; ++nt)
#pragma unroll
      for (int ks = 0; ks < 6; ++ks) {
        bf16x8 bf = *(const bf16x8*)(cb + ((nw * 2 + nt) * 6 + ks) * 512 + lane * 8);
        S[0][nt] = MFMA16(afr[0][ks], bf, S[0][nt]);
        S[1][nt] = MFMA16(afr[1][ks], bf, S[1][nt]);
      }
    int which = j / 3;  // 0=q 1=k 2=v
    u16* dst = which == 0 ? qb : (which == 1 ? kb : vb);
#pragma unroll
    for (int nt = 0; nt < 2; ++nt) {
      int jc = j * 64 + nw * 32 + nt * 16 + c;
      int jj = jc - which * 192;
      int hh = jj >> 5, d = jj & 31;
      float bv = qkvb_[jc];
#pragma unroll
      for (int rt = 0; rt < 2; ++rt)
#pragma unroll
        for (int reg = 0; reg < 4; ++reg) {
          int rg = tok0 + m0 + mw * 32 + rt * 16 + 4 * g + reg;
          int win = rg / 49, n = rg - win * 49;
          dst[((size_t)((win - win0) * 6 + hh) * 49 + n) * 32 + d] =
              f2b(S[rt][nt][reg] + bv);
        }
    }
    __syncthreads();  // stage(j+1) drained; cb reads done
  }
}

// ---------------- attention: one (window, head) per block (unchanged) ------
__global__ __launch_bounds__(256) void attn_kernel(
    const u16* __restrict__ qb, const u16* __restrict__ kb,
    const u16* __restrict__ vb, const float* __restrict__ rpb,
    const float* __restrict__ amask, u16* __restrict__ aout, int win0) {
  __shared__ __align__(16) u16 qs[64 * 32], ks[64 * 32], vst[32 * 64];
  __shared__ __align__(16) float S[64 * 68];
  __shared__ __align__(16) u16 P[64 * 64];
  int tid = threadIdx.x;
  int blk = blockIdx.x;
  int winl = blk / 6, head = blk - winl * 6;
  int wi = (win0 + winl) & 63;
  const size_t base = (size_t)(winl * 6 + head) * 49 * 32;
  {
    int row = tid >> 2, kcl = tid & 3;
    int phys = kcl ^ (row & 3);
    uint4 qv = make_uint4(0, 0, 0, 0), kv = qv, vv = qv;
    if (row < 49) {
      size_t o = base + (size_t)row * 32 + kcl * 8;
      qv = *(const uint4*)(qb + o);
      kv = *(const uint4*)(kb + o);
      vv = *(const uint4*)(vb + o);
    }
    *(uint4*)(qs + row * 32 + phys * 8) = qv;
    *(uint4*)(ks + row * 32 + phys * 8) = kv;
    alignas(16) u16 vu[8];
    *(uint4*)vu = vv;
    int c8 = kcl * 8;
    int kc = row >> 3;
#pragma unroll
    for (int j = 0; j < 8; ++j) {
      int d = c8 + j;
      vst[d * 64 + ((kc ^ (d & 7)) * 8) + (row & 7)] = vu[j];
    }
  }
  __syncthreads();
  int wave = tid >> 6, lane = tid & 63;
  int col = lane & 15, g = lane >> 4;
  {
    int ar = wave * 16 + col;
    bf16x8 af = *(const bf16x8*)(qs + ar * 32 + ((g ^ (ar & 3)) * 8));
    f32x4 zero = {0.f, 0.f, 0.f, 0.f};
#pragma unroll
    for (int nt = 0; nt < 4; ++nt) {
      int br = nt * 16 + col;
      bf16x8 bfr = *(const bf16x8*)(ks + br * 32 + ((g ^ (br & 3)) * 8));
      f32x4 sacc = MFMA16(af, bfr, zero);
#pragma unroll
      for (int reg = 0; reg < 4; ++reg)
        S[(wave * 16 + 4 * g + reg) * 68 + nt * 16 + col] = sacc[reg];
    }
  }
  __syncthreads();
  {
    int r = tid >> 2, p = tid & 3;
    int rb = (r < 49) ? r : 0;
    int i1 = rb / 7, j1 = rb - i1 * 7;
    const float scale = 0.17677669529663687f;
    const float* Srow = S + r * 68;
    float vals[16];
    float mx = -1e30f;
#pragma unroll
    for (int t = 0; t < 16; ++t) {
      int cc = p * 16 + t;
      float v = -1e30f;
      if (cc < 49) {
        int i2 = cc / 7, j2 = cc - i2 * 7;
        int ridx = (i1 - i2 + 6) * 13 + (j1 - j2 + 6);
        v = Srow[cc] * scale + rpb[ridx * 6 + head] +
            amask[(size_t)wi * 2401 + rb * 49 + cc];
      }
      vals[t] = v;
      mx = fmaxf(mx, v);
    }
    mx = fmaxf(mx, __shfl_xor(mx, 1, 64));
    mx = fmaxf(mx, __shfl_xor(mx, 2, 64));
    float se = 0.f;
#pragma unroll
    for (int t = 0; t < 16; ++t) {
      float e = __expf(vals[t] - mx);
      vals[t] = e;
      se += e;
    }
    se += __shfl_xor(se, 1, 64);
    se += __shfl_xor(se, 2, 64);
    float inv = 1.0f / se;
#pragma unroll
    for (int t = 0; t < 16; ++t) {
      int cc = p * 16 + t;
      P[r * 64 + (((cc >> 3) ^ (r & 7)) * 8) + (cc & 7)] = f2b(vals[t] * inv);
    }
  }
  __syncthreads();
  {
    f32x4 oacc[2] = {{0,0,0,0},{0,0,0,0}};
    int ar = wave * 16 + col;
#pragma unroll
    for (int kt = 0; kt < 2; ++kt) {
      bf16x8 pf = *(const bf16x8*)(P + ar * 64 + (((kt * 4 + g) ^ (ar & 7)) * 8));
#pragma unroll
      for (int nt = 0; nt < 2; ++nt) {
        int d = nt * 16 + col;
        bf16x8 vf = *(const bf16x8*)(vst + d * 64 + (((kt * 4 + g) ^ (d & 7)) * 8));
        oacc[nt] = MFMA16(pf, vf, oacc[nt]);
      }
    }
#pragma unroll
    for (int nt = 0; nt < 2; ++nt)
#pragma unroll
      for (int reg = 0; reg < 4; ++reg) {
        int rloc = wave * 16 + 4 * g + reg;
        if (rloc < 49)
          aout[((size_t)winl * 49 + rloc) * 192 + head * 32 + nt * 16 + col] =
              f2b(oacc[nt][reg]);
      }
  }
}

// ---------------- fused proj + window reverse + unshift + residual ---------
__global__ __launch_bounds__(256, 3) void proj_fused(
    const u16* __restrict__ aout, const u16* __restrict__ wf,
    const float* __restrict__ pb, const float* __restrict__ x,
    float* __restrict__ out, int tok0) {
  __shared__ __align__(16) u16 lds[24576];  // 48 KB
  u16* sA = lds;
  u16* b0 = lds;
  u16* b1 = lds + 12288;
  int tid = threadIdx.x, wave = tid >> 6, lane = tid & 63;
  int g = lane >> 4, c = lane & 15;
  int m0 = blockIdx.x * 64;
  stage_64x192(aout + (size_t)m0 * 192, 192, sA, wave, lane);
  asm volatile("s_waitcnt vmcnt(0)" ::: "memory");
  __syncthreads();
  int mw = wave >> 1, nw = wave & 1;
  bf16x8 afr[2][6];
#pragma unroll
  for (int rt = 0; rt < 2; ++rt) {
    int ar = mw * 32 + rt * 16 + c;
#pragma unroll
    for (int ks = 0; ks < 6; ++ks) {
      int ch = ks * 4 + g;
      int ph = (ch & 24) | ((ch ^ (ar & 7)) & 7);
      afr[rt][ks] = *(const bf16x8*)(sA + ar * 192 + ph * 8);
    }
  }
  size_t trow[2][4];
#pragma unroll
  for (int rt = 0; rt < 2; ++rt)
#pragma unroll
    for (int reg = 0; reg < 4; ++reg) {
      int rg = tok0 + m0 + mw * 32 + rt * 16 + 4 * g + reg;
      int win = rg / 49, n = rg - win * 49;
      int b_ = win >> 6, wi = win & 63;
      int wh = wi >> 3, ww = wi & 7;
      int rr = n / 7, cc = n - rr * 7;
      int hd_ = wh * 7 + rr + 3; if (hd_ >= 56) hd_ -= 56;
      int wd = ww * 7 + cc + 3; if (wd >= 56) wd -= 56;
      trow[rt][reg] = (size_t)b_ * 3136 + hd_ * 56 + wd;
    }
  __syncthreads();  // afr reads done -> sA region (b0) reusable
  stage_frags<24>(wf, b0, wave, lane);
  __syncthreads();  // b0 staged
  for (int j = 0; j < 3; ++j) {
    const u16* cb = (j & 1) ? b1 : b0;
    if (j < 2)
      stage_frags<24>(wf + (size_t)(j + 1) * 24 * 512, (j & 1) ? b0 : b1, wave,
                      lane);
    f32x4 S[2][2] = {{{0,0,0,0},{0,0,0,0}},{{0,0,0,0},{0,0,0,0}}};
#pragma unroll
    for (int nt = 0; nt < 2; ++nt)
#pragma unroll
      for (int ks = 0; ks < 6; ++ks) {
        bf16x8 bf = *(const bf16x8*)(cb + ((nw * 2 + nt) * 6 + ks) * 512 + lane * 8);
        S[0][nt] = MFMA16(afr[0][ks], bf, S[0][nt]);
        S[1][nt] = MFMA16(afr[1][ks], bf, S[1][nt]);
      }
#pragma unroll
    for (int nt = 0; nt < 2; ++nt) {
      int jc = j * 64 + nw * 32 + nt * 16 + c;
      float bv = pb[jc];
#pragma unroll
      for (int rt = 0; rt < 2; ++rt)
#pragma unroll
        for (int reg = 0; reg < 4; ++reg) {
          size_t o = trow[rt][reg] * 192 + jc;
          out[o] = x[o] + S[rt][nt][reg] + bv;
        }
    }
    __syncthreads();
  }
}

// ---------------- fused LN2 + fc1 + GELU + fc2 + residual ------------------
// Swapped-operand, M=64/block, fc1 via LDS dbuf, fc2 via per-wave register
// prefetch from L2/L1 (issued at phase top, consumed after fc1+GELU).
__global__ __launch_bounds__(256, 3) void mlp_fused(
    const float* __restrict__ n2w, const float* __restrict__ n2b,
    const u16* __restrict__ w1f, const float* __restrict__ b1,
    const u16* __restrict__ w2f, const float* __restrict__ b2,
    float* __restrict__ out) {
  __shared__ __align__(16) u16 lds[12288];  // 24 KB: fc1 dbuf; sA overlays both
  u16* c1a = lds;            // 12 frags (6144 u16)
  u16* c1b = lds + 6144;
  u16* sA  = lds;            // 64x192 overlay (12288 u16)
  int tid = threadIdx.x, wave = tid >> 6, lane = tid & 63;
  int g = lane >> 4, c = lane & 15, wr = wave * 16;
  int m0 = blockIdx.x * 64;
  // --- LN2: wave owns 16 rows -> sA swizzled ---
  {
    float v[12][4];
    int rr[4];
#pragma unroll
    for (int reg = 0; reg < 4; ++reg) rr[reg] = m0 + wr + 4 * g + reg;
#pragma unroll
    for (int nt = 0; nt < 12; ++nt)
#pragma unroll
      for (int reg = 0; reg < 4; ++reg)
        v[nt][reg] = out[(size_t)rr[reg] * 192 + nt * 16 + c];
#pragma unroll
    for (int reg = 0; reg < 4; ++reg) {
      float s = 0.f;
#pragma unroll
      for (int nt = 0; nt < 12; ++nt) s += v[nt][reg];
      s += __shfl_xor(s, 1, 64); s += __shfl_xor(s, 2, 64);
      s += __shfl_xor(s, 4, 64); s += __shfl_xor(s, 8, 64);
      float m = s * (1.f / 192.f), q = 0.f;
#pragma unroll
      for (int nt = 0; nt < 12; ++nt) { float d = v[nt][reg] - m; q += d * d; }
      q += __shfl_xor(q, 1, 64); q += __shfl_xor(q, 2, 64);
      q += __shfl_xor(q, 4, 64); q += __shfl_xor(q, 8, 64);
      float rs = rsqrtf(q * (1.f / 192.f) + 1e-5f);
#pragma unroll
      for (int nt = 0; nt < 12; ++nt) v[nt][reg] = (v[nt][reg] - m) * rs;
    }
#pragma unroll
    for (int nt = 0; nt < 12; ++nt) {
      float wv = n2w[nt * 16 + c], bv = n2b[nt * 16 + c];
#pragma unroll
      for (int reg = 0; reg < 4; ++reg) {
        int r = wr + 4 * g + reg;
        int ch = nt * 2 + (c >> 3);
        int ph = (ch & 24) | ((ch ^ (r & 7)) & 7);
        sA[r * 192 + ph * 8 + (c & 7)] = f2b(v[nt][reg] * wv + bv);
      }
    }
  }
  __syncthreads();  // sA visible
  // A-frags for this wave's 16 m-rows (B-operand of swapped fc1)
  bf16x8 afr[6];
  {
    int ar = wr + c;
#pragma unroll
    for (int ks = 0; ks < 6; ++ks) {
      int ch = ks * 4 + g;
      int ph = (ch & 24) | ((ch ^ (ar & 7)) & 7);
      afr[ks] = *(const bf16x8*)(sA + ar * 192 + ph * 8);
    }
  }
  __syncthreads();  // all afr reads done -> sA region (c1a/c1b) reusable
  stage_frags<12>(w1f, c1a, wave, lane);
  f32x4 o[12];
#pragma unroll
  for (int i = 0; i < 12; ++i) o[i] = (f32x4){0.f, 0.f, 0.f, 0.f};
  __syncthreads();  // prologue stage drained
  for (int j = 0; j < 24; ++j) {
    int cur = j & 1;
    const u16* r1 = cur ? c1b : c1a;
    // ---- fc2 register prefetch (this phase): 12 independent 16B loads,
    // consumed after fc1+GELU (~1000 cy cover). All waves read same 12KB
    // -> wave 0 L2, waves 1-3 L1 hits.
    bf16x8 wf2[12];
#pragma unroll
    for (int ct = 0; ct < 12; ++ct)
      wf2[ct] = *(const bf16x8*)(w2f + (size_t)j * 6144 + ct * 512 + lane * 8);
    if (j < 23)
      stage_frags<12>(w1f + (size_t)(j + 1) * 6144, cur ? c1a : c1b, wave, lane);
    // ---- swapped fc1: S1[ht] = W1_frag x afr -> lane holds P^T[h][m=wr+c] ----
    f32x4 S1[2] = {{0,0,0,0},{0,0,0,0}};
#pragma unroll
    for (int ks = 0; ks < 6; ++ks) {
      bf16x8 w0 = *(const bf16x8*)(r1 + (0 * 6 + ks) * 512 + lane * 8);
      bf16x8 w1v = *(const bf16x8*)(r1 + (1 * 6 + ks) * 512 + lane * 8);
      S1[0] = MFMA16(w0, afr[ks], S1[0]);
      S1[1] = MFMA16(w1v, afr[ks], S1[1]);
    }
    // ---- GELU + lane-local bf16 pack: pf slot (g,i) = h pi(g,i) ----
    union { u16 h[8]; bf16x8 v; } pu;
    float4 bv0 = *(const float4*)(b1 + j * 32 + 4 * g);
    float4 bv1 = *(const float4*)(b1 + j * 32 + 16 + 4 * g);
#pragma unroll
    for (int r = 0; r < 4; ++r) {
      float v0 = S1[0][r] + ((const float*)&bv0)[r];
      float u20 = v0 * (1.5957691216f + 0.0713548163f * v0 * v0);
      pu.h[r] = f2b(v0 / (1.f + __expf(-u20)));
      float v1 = S1[1][r] + ((const float*)&bv1)[r];
      float u21 = v1 * (1.5957691216f + 0.0713548163f * v1 * v1);
      pu.h[r + 4] = f2b(v1 / (1.f + __expf(-u21)));
    }
    // ---- swapped PV: o[ct] += W2_frag(pi-packed, in regs) x pf ----
#pragma unroll
    for (int ct = 0; ct < 12; ++ct)
      o[ct] = MFMA16(wf2[ct], pu.v, o[ct]);
    __syncthreads();  // r1 reads done; fc1 stage(j+1) drained
  }
  // epilogue: lane holds O^T[cout=ct*16+4g+r][m=wr+c]; float4 residual RMW
  float* rowp = out + (size_t)(m0 + wr + c) * 192;
#pragma unroll
  for (int ct = 0; ct < 12; ++ct) {
    float4* p = (float4*)(rowp + ct * 16 + 4 * g);
    float4 cu = *p;
    float4 b4 = *(const float4*)(b2 + ct * 16 + 4 * g);
    cu.x += o[ct][0] + b4.x;
    cu.y += o[ct][1] + b4.y;
    cu.z += o[ct][2] + b4.z;
    cu.w += o[ct][3] + b4.w;
    *p = cu;
  }
}

extern "C" void kernel_launch(void* const* d_in, const int* in_sizes, int n_in,
                              void* d_out, int out_size, void* d_ws, size_t ws_size,
                              hipStream_t stream) {
  (void)in_sizes; (void)n_in; (void)out_size;
  const float* x     = (const float*)d_in[0];
  const float* amask = (const float*)d_in[1];
  const float* n1w   = (const float*)d_in[2];
  const float* n1b   = (const float*)d_in[3];
  const float* qkvw  = (const float*)d_in[4];
  const float* qkvb  = (const float*)d_in[5];
  const float* rpb   = (const float*)d_in[6];
  const float* projw = (const float*)d_in[7];
  const float* projb = (const float*)d_in[8];
  const float* n2w   = (const float*)d_in[9];
  const float* n2b   = (const float*)d_in[10];
  const float* fc1w  = (const float*)d_in[11];
  const float* fc1b  = (const float*)d_in[12];
  const float* fc2w  = (const float*)d_in[13];
  const float* fc2b  = (const float*)d_in[14];
  float* out = (float*)d_out;
  char* ws = (char*)d_ws;

  u16* qkvwf = (u16*)(ws);                               // ct-major 36x6
  u16* projwf = (u16*)(ws + 221184);                     // ct-major 12x6
  u16* fc1wf = (u16*)(ws + 221184 + 73728);              // ct-major 48x6
  u16* fc2wf = (u16*)(ws + 221184 + 73728 + 294912);     // pi-packed hs-major 24x12
  char* arena = ws + (1 << 20);
  size_t arena_sz = ws_size > (1 << 20) ? ws_size - (1 << 20) : 0;

  pack_kernel<<<(36 * 6 * 64 + 255) / 256, 256, 0, stream>>>(qkvw, qkvwf, 36, 6, 192, 0);
  pack_kernel<<<(12 * 6 * 64 + 255) / 256, 256, 0, stream>>>(projw, projwf, 12, 6, 192, 0);
  pack_kernel<<<(48 * 6 * 64 + 255) / 256, 256, 0, stream>>>(fc1w, fc1wf, 48, 6, 192, 0);
  pack2_kernel<<<(24 * 12 * 64 + 255) / 256, 256, 0, stream>>>(fc2w, fc2wf);

  // ---- attention path, chunked over window groups (ws-size adaptive) ----
  int NCA = 1;
  while (NCA < 16 && 4ull * (size_t)(2048 / NCA) * 49 * 192 * 2 > arena_sz)
    NCA <<= 1;
  int Wc = 2048 / NCA;
  size_t Sx = (size_t)Wc * 49 * 192;  // u16 elements per buffer
  for (int cch = 0; cch < NCA; ++cch) {
    int win0 = cch * Wc;
    int tok0 = win0 * 49;
    u16* aout_c = (u16*)arena;
    u16* qb = (u16*)arena + Sx;
    u16* kb = qb + Sx;
    u16* vb = kb + Sx;
    int rows = Wc * 49;
    qkv_fused<<<rows / 64, 256, 0, stream>>>(x, n1w, n1b, qkvwf, qkvb,
                                             qb, kb, vb, tok0);
    attn_kernel<<<Wc * 6, 256, 0, stream>>>(qb, kb, vb, rpb, amask, aout_c,
                                            win0);
    proj_fused<<<rows / 64, 256, 0, stream>>>(aout_c, projwf, projb, x, out,
                                              tok0);
  }

  // ---- fused MLP: swapped operands, fc2 in registers, 24KB LDS ----
  mlp_fused<<<1568, 256, 0, stream>>>(n2w, n2b, fc1wf, fc1b, fc2wf, fc2b,
                                      out);
}

// Round 13
// 339.375 us; speedup vs baseline: 1.3412x; 1.3412x over previous
//
#include <hip/hip_runtime.h>
#include <hip/hip_bf16.h>

typedef unsigned short u16;
typedef __attribute__((ext_vector_type(8))) short bf16x8;
typedef __attribute__((ext_vector_type(4))) float f32x4;

#define MFMA16(a, b, c) __builtin_amdgcn_mfma_f32_16x16x32_bf16(a, b, c, 0, 0, 0)

__device__ __forceinline__ u16 f2b(float f) {
  union { float f; unsigned u; } x; x.f = f;
  return (u16)((x.u + 0x7fffu + ((x.u >> 16) & 1u)) >> 16);
}

__device__ __forceinline__ void gload_lds16(const void* g, void* l) {
  __builtin_amdgcn_global_load_lds(
      (const __attribute__((address_space(1))) void*)g,
      (__attribute__((address_space(3))) void*)l, 16, 0, 0);
}

// linear frag-block stage: NCH chunks of 512 u16 (64 lanes x 16B), src contiguous
template <int NCH>
__device__ __forceinline__ void stage_frags(const u16* __restrict__ src,
                                            u16* dst, int wave, int lane) {
#pragma unroll
  for (int it = 0; it < NCH / 4; ++it) {
    int chunk = it * 4 + wave;
    gload_lds16(src + ((size_t)chunk * 64 + lane) * 8, dst + chunk * 512);
  }
}

// stage 64 rows x 192 cols bf16 -> LDS, chunk XOR-swizzled by row&7 (proj A).
__device__ __forceinline__ void stage_64x192(const u16* __restrict__ src,
                                             int stride, u16* dst, int wave,
                                             int lane) {
#pragma unroll
  for (int it = 0; it < 6; ++it) {
    int id = (it * 4 + wave) * 64 + lane;
    int row = id / 24, ph = id - row * 24;
    int lch = (ph & 24) | ((ph ^ (row & 7)) & 7);
    gload_lds16(src + (size_t)row * stride + lch * 8,
                dst + (it * 4 + wave) * 512);
  }
}

// ---------------- weight fp32 -> bf16 MFMA-fragment order ------------------
__global__ __launch_bounds__(256) void pack_kernel(const float* __restrict__ W,
                                                   u16* __restrict__ F, int NT,
                                                   int KS, int K, int kmajor) {
  int f = blockIdx.x * 256 + threadIdx.x;
  if (f >= NT * KS * 64) return;
  int l = f & 63, rest = f >> 6;
  int ks, ct;
  if (kmajor) { ct = rest % NT; ks = rest / NT; }
  else        { ks = rest % KS; ct = rest / KS; }
  int row = ct * 16 + (l & 15);
  int col = ks * 32 + (l >> 4) * 8;
  const float* s = W + (size_t)row * K + col;
  u16* d = F + (size_t)f * 8;
#pragma unroll
  for (int i = 0; i < 8; ++i) d[i] = f2b(s[i]);
}

// fc2 pack with pi-permuted k within each 32-h chunk (matches lane-local pf):
// pi(g,i) = 4g+i (i<4), 16+4g+(i-4) (i>=4). frag id = hs*12 + ct.
__global__ __launch_bounds__(256) void pack2_kernel(const float* __restrict__ W,
                                                    u16* __restrict__ F) {
  int f = blockIdx.x * 256 + threadIdx.x;
  if (f >= 24 * 12 * 64) return;
  int l = f & 63, rest = f >> 6;
  int ct = rest % 12, hs = rest / 12;
  int row = ct * 16 + (l & 15);
  int g = l >> 4;
  u16* d = F + (size_t)f * 8;
#pragma unroll
  for (int i = 0; i < 8; ++i) {
    int h = hs * 32 + (i < 4 ? 4 * g + i : 16 + 4 * g + (i - 4));
    d[i] = f2b(W[(size_t)row * 768 + h]);
  }
}

// ---------------- fused LN1 + shift/window + QKV + attention ---------------
// One block per window; 6-head loop inside. q/k/v never touch HBM.
__global__ __launch_bounds__(256, 3) void attn_win(
    const float* __restrict__ x, const float* __restrict__ n1w,
    const float* __restrict__ n1b, const u16* __restrict__ qkvwf,
    const float* __restrict__ qkvb_, const float* __restrict__ rpb,
    const float* __restrict__ amask, u16* __restrict__ aout, int win0) {
  __shared__ __align__(16) u16 lds[18944];  // 37,888 B
  u16* sA  = lds;                 // 64x192 swizzled (12288 u16); dead after afr
  u16* qs  = lds;                 // 64x32 (2048 u16)  -- overlays sA
  u16* ksm = lds + 2048;          // 64x32
  u16* vst = lds + 4096;          // 32x64 transposed
  u16* P   = lds + 6144;          // 64x64 (4096 u16)
  float* Sf = (float*)(lds + 10240);  // 64x68 f32 (17408 B)
  int tid = threadIdx.x, wave = tid >> 6, lane = tid & 63;
  int g = lane >> 4, c = lane & 15, wr = wave * 16;
  int blk = blockIdx.x;
  int wing = win0 + blk;          // global window index
  int wi = wing & 63;
  // --- LN1 for this window's 64 rows (49 real + 15 clamped-dup) -> sA ---
  {
    float vals[12][4];
    int srcrow[4];
#pragma unroll
    for (int reg = 0; reg < 4; ++reg) {
      int n = wr + 4 * g + reg;
      if (n > 48) n = 48;  // pad rows: duplicate token 48 (finite, masked later)
      int bb = wing >> 6, wloc = wing & 63, wh = wloc >> 3, ww = wloc & 7;
      int rr = n / 7, cc = n - rr * 7;
      int hs = wh * 7 + rr + 3; if (hs >= 56) hs -= 56;
      int wsr = ww * 7 + cc + 3; if (wsr >= 56) wsr -= 56;
      srcrow[reg] = bb * 3136 + hs * 56 + wsr;
    }
#pragma unroll
    for (int nt = 0; nt < 12; ++nt)
#pragma unroll
      for (int reg = 0; reg < 4; ++reg)
        vals[nt][reg] = x[(size_t)srcrow[reg] * 192 + nt * 16 + c];
#pragma unroll
    for (int reg = 0; reg < 4; ++reg) {
      float s = 0.f;
#pragma unroll
      for (int nt = 0; nt < 12; ++nt) s += vals[nt][reg];
      s += __shfl_xor(s, 1, 64); s += __shfl_xor(s, 2, 64);
      s += __shfl_xor(s, 4, 64); s += __shfl_xor(s, 8, 64);
      float m = s * (1.f / 192.f), q = 0.f;
#pragma unroll
      for (int nt = 0; nt < 12; ++nt) { float d = vals[nt][reg] - m; q += d * d; }
      q += __shfl_xor(q, 1, 64); q += __shfl_xor(q, 2, 64);
      q += __shfl_xor(q, 4, 64); q += __shfl_xor(q, 8, 64);
      float rs = rsqrtf(q * (1.f / 192.f) + 1e-5f);
#pragma unroll
      for (int nt = 0; nt < 12; ++nt) vals[nt][reg] = (vals[nt][reg] - m) * rs;
    }
#pragma unroll
    for (int nt = 0; nt < 12; ++nt) {
      float wv = n1w[nt * 16 + c], bv = n1b[nt * 16 + c];
#pragma unroll
      for (int reg = 0; reg < 4; ++reg) {
        int r = wr + 4 * g + reg;
        int ch = nt * 2 + (c >> 3);
        int ph = (ch & 24) | ((ch ^ (r & 7)) & 7);
        sA[r * 192 + ph * 8 + (c & 7)] = f2b(vals[nt][reg] * wv + bv);
      }
    }
  }
  __syncthreads();  // sA visible
  // A-frags for this wave's 16 rows (reused for all 6 heads)
  bf16x8 afr[6];
  {
    int ar = wr + c;
#pragma unroll
    for (int ks = 0; ks < 6; ++ks) {
      int ch = ks * 4 + g;
      int ph = (ch & 24) | ((ch ^ (ar & 7)) & 7);
      afr[ks] = *(const bf16x8*)(sA + ar * 192 + ph * 8);
    }
  }
  __syncthreads();  // afr loads done -> sA region reusable as attn buffers
  int col = c;      // alias used by attn body
  for (int h = 0; h < 6; ++h) {
    // ---- qkv for head h: per wave, its 16 rows x {q,k,v} x 2 ct tiles ----
#pragma unroll
    for (int s = 0; s < 3; ++s) {
#pragma unroll
      for (int t = 0; t < 2; ++t) {
        int ct = s * 12 + h * 2 + t;
        f32x4 acc = {0.f, 0.f, 0.f, 0.f};
#pragma unroll
        for (int ks = 0; ks < 6; ++ks) {
          bf16x8 wfq =
              *(const bf16x8*)(qkvwf + ((size_t)(ct * 6 + ks) * 64 + lane) * 8);
          acc = MFMA16(afr[ks], wfq, acc);
        }
        float bv = qkvb_[s * 192 + h * 32 + t * 16 + c];
        int d = t * 16 + c;
#pragma unroll
        for (int reg = 0; reg < 4; ++reg) {
          int r = wr + 4 * g + reg;
          u16 val = f2b(acc[reg] + bv);
          if (s == 0)
            qs[r * 32 + (((d >> 3) ^ (r & 3)) * 8) + (d & 7)] = val;
          else if (s == 1)
            ksm[r * 32 + (((d >> 3) ^ (r & 3)) * 8) + (d & 7)] = val;
          else
            vst[d * 64 + (((r >> 3) ^ (d & 7)) * 8) + (r & 7)] = val;
        }
      }
    }
    __syncthreads();  // q/k/v tiles visible
    // ---- S = q @ k^T ----
    {
      int ar = wr + col;
      bf16x8 af = *(const bf16x8*)(qs + ar * 32 + ((g ^ (ar & 3)) * 8));
      f32x4 zero = {0.f, 0.f, 0.f, 0.f};
#pragma unroll
      for (int nt = 0; nt < 4; ++nt) {
        int br = nt * 16 + col;
        bf16x8 bfr = *(const bf16x8*)(ksm + br * 32 + ((g ^ (br & 3)) * 8));
        f32x4 sacc = MFMA16(af, bfr, zero);
#pragma unroll
        for (int reg = 0; reg < 4; ++reg)
          Sf[(wr + 4 * g + reg) * 68 + nt * 16 + col] = sacc[reg];
      }
    }
    __syncthreads();
    // ---- softmax with rel-pos bias + shift mask ----
    {
      int r = tid >> 2, p = tid & 3;
      int rb = (r < 49) ? r : 0;
      int i1 = rb / 7, j1 = rb - i1 * 7;
      const float scale = 0.17677669529663687f;
      const float* Srow = Sf + r * 68;
      float vals[16];
      float mx = -1e30f;
#pragma unroll
      for (int t = 0; t < 16; ++t) {
        int cc = p * 16 + t;
        float v = -1e30f;
        if (cc < 49) {
          int i2 = cc / 7, j2 = cc - i2 * 7;
          int ridx = (i1 - i2 + 6) * 13 + (j1 - j2 + 6);
          v = Srow[cc] * scale + rpb[ridx * 6 + h] +
              amask[(size_t)wi * 2401 + rb * 49 + cc];
        }
        vals[t] = v;
        mx = fmaxf(mx, v);
      }
      mx = fmaxf(mx, __shfl_xor(mx, 1, 64));
      mx = fmaxf(mx, __shfl_xor(mx, 2, 64));
      float se = 0.f;
#pragma unroll
      for (int t = 0; t < 16; ++t) {
        float e = __expf(vals[t] - mx);
        vals[t] = e;
        se += e;
      }
      se += __shfl_xor(se, 1, 64);
      se += __shfl_xor(se, 2, 64);
      float inv = 1.0f / se;
#pragma unroll
      for (int t = 0; t < 16; ++t) {
        int cc = p * 16 + t;
        P[r * 64 + (((cc >> 3) ^ (r & 7)) * 8) + (cc & 7)] = f2b(vals[t] * inv);
      }
    }
    __syncthreads();
    // ---- O = P @ V -> aout ----
    {
      f32x4 oacc[2] = {{0, 0, 0, 0}, {0, 0, 0, 0}};
      int ar = wr + col;
#pragma unroll
      for (int kt = 0; kt < 2; ++kt) {
        bf16x8 pf =
            *(const bf16x8*)(P + ar * 64 + (((kt * 4 + g) ^ (ar & 7)) * 8));
#pragma unroll
        for (int nt = 0; nt < 2; ++nt) {
          int d = nt * 16 + col;
          bf16x8 vf =
              *(const bf16x8*)(vst + d * 64 + (((kt * 4 + g) ^ (d & 7)) * 8));
          oacc[nt] = MFMA16(pf, vf, oacc[nt]);
        }
      }
#pragma unroll
      for (int nt = 0; nt < 2; ++nt)
#pragma unroll
        for (int reg = 0; reg < 4; ++reg) {
          int rloc = wr + 4 * g + reg;
          if (rloc < 49)
            aout[((size_t)blk * 49 + rloc) * 192 + h * 32 + nt * 16 + col] =
                f2b(oacc[nt][reg]);
        }
    }
    __syncthreads();  // PV reads done -> next head may overwrite q/k/v tiles
  }
}

// ---------------- fused proj + window reverse + unshift + residual ---------
__global__ __launch_bounds__(256, 3) void proj_fused(
    const u16* __restrict__ aout, const u16* __restrict__ wf,
    const float* __restrict__ pb, const float* __restrict__ x,
    float* __restrict__ out, int tok0) {
  __shared__ __align__(16) u16 lds[24576];  // 48 KB
  u16* sA = lds;
  u16* b0 = lds;
  u16* b1 = lds + 12288;
  int tid = threadIdx.x, wave = tid >> 6, lane = tid & 63;
  int g = lane >> 4, c = lane & 15;
  int m0 = blockIdx.x * 64;
  stage_64x192(aout + (size_t)m0 * 192, 192, sA, wave, lane);
  asm volatile("s_waitcnt vmcnt(0)" ::: "memory");
  __syncthreads();
  int mw = wave >> 1, nw = wave & 1;
  bf16x8 afr[2][6];
#pragma unroll
  for (int rt = 0; rt < 2; ++rt) {
    int ar = mw * 32 + rt * 16 + c;
#pragma unroll
    for (int ks = 0; ks < 6; ++ks) {
      int ch = ks * 4 + g;
      int ph = (ch & 24) | ((ch ^ (ar & 7)) & 7);
      afr[rt][ks] = *(const bf16x8*)(sA + ar * 192 + ph * 8);
    }
  }
  size_t trow[2][4];
#pragma unroll
  for (int rt = 0; rt < 2; ++rt)
#pragma unroll
    for (int reg = 0; reg < 4; ++reg) {
      int rg = tok0 + m0 + mw * 32 + rt * 16 + 4 * g + reg;
      int win = rg / 49, n = rg - win * 49;
      int b_ = win >> 6, wi = win & 63;
      int wh = wi >> 3, ww = wi & 7;
      int rr = n / 7, cc = n - rr * 7;
      int hd_ = wh * 7 + rr + 3; if (hd_ >= 56) hd_ -= 56;
      int wd = ww * 7 + cc + 3; if (wd >= 56) wd -= 56;
      trow[rt][reg] = (size_t)b_ * 3136 + hd_ * 56 + wd;
    }
  __syncthreads();  // afr reads done -> sA region (b0) reusable
  stage_frags<24>(wf, b0, wave, lane);
  __syncthreads();  // b0 staged
  for (int j = 0; j < 3; ++j) {
    const u16* cb = (j & 1) ? b1 : b0;
    if (j < 2)
      stage_frags<24>(wf + (size_t)(j + 1) * 24 * 512, (j & 1) ? b0 : b1, wave,
                      lane);
    f32x4 S[2][2] = {{{0,0,0,0},{0,0,0,0}},{{0,0,0,0},{0,0,0,0}}};
#pragma unroll
    for (int nt = 0; nt < 2; ++nt)
#pragma unroll
      for (int ks = 0; ks < 6; ++ks) {
        bf16x8 bf = *(const bf16x8*)(cb + ((nw * 2 + nt) * 6 + ks) * 512 + lane * 8);
        S[0][nt] = MFMA16(afr[0][ks], bf, S[0][nt]);
        S[1][nt] = MFMA16(afr[1][ks], bf, S[1][nt]);
      }
#pragma unroll
    for (int nt = 0; nt < 2; ++nt) {
      int jc = j * 64 + nw * 32 + nt * 16 + c;
      float bv = pb[jc];
#pragma unroll
      for (int rt = 0; rt < 2; ++rt)
#pragma unroll
        for (int reg = 0; reg < 4; ++reg) {
          size_t o = trow[rt][reg] * 192 + jc;
          out[o] = x[o] + S[rt][nt][reg] + bv;
        }
    }
    __syncthreads();
  }
}

// ---------------- fused LN2 + fc1 + GELU + fc2 + residual (r10 exact) ------
__global__ __launch_bounds__(256, 3) void mlp_fused(
    const float* __restrict__ n2w, const float* __restrict__ n2b,
    const u16* __restrict__ w1f, const float* __restrict__ b1,
    const u16* __restrict__ w2f, const float* __restrict__ b2,
    float* __restrict__ out) {
  __shared__ __align__(16) u16 lds[24576];  // 48 KB
  u16* c1a = lds;            // 12 frags (6144 u16) fc1 buf0
  u16* c1b = lds + 6144;
  u16* c2a = lds + 12288;    // fc2 buf0
  u16* c2b = lds + 18432;
  u16* sA  = lds;            // 64x192 overlay (c1a+c1b), dead after afr loads
  int tid = threadIdx.x, wave = tid >> 6, lane = tid & 63;
  int g = lane >> 4, c = lane & 15, wr = wave * 16;
  int m0 = blockIdx.x * 64;
  // --- LN2: wave owns 16 rows -> sA swizzled ---
  {
    float v[12][4];
    int rr[4];
#pragma unroll
    for (int reg = 0; reg < 4; ++reg) rr[reg] = m0 + wr + 4 * g + reg;
#pragma unroll
    for (int nt = 0; nt < 12; ++nt)
#pragma unroll
      for (int reg = 0; reg < 4; ++reg)
        v[nt][reg] = out[(size_t)rr[reg] * 192 + nt * 16 + c];
#pragma unroll
    for (int reg = 0; reg < 4; ++reg) {
      float s = 0.f;
#pragma unroll
      for (int nt = 0; nt < 12; ++nt) s += v[nt][reg];
      s += __shfl_xor(s, 1, 64); s += __shfl_xor(s, 2, 64);
      s += __shfl_xor(s, 4, 64); s += __shfl_xor(s, 8, 64);
      float m = s * (1.f / 192.f), q = 0.f;
#pragma unroll
      for (int nt = 0; nt < 12; ++nt) { float d = v[nt][reg] - m; q += d * d; }
      q += __shfl_xor(q, 1, 64); q += __shfl_xor(q, 2, 64);
      q += __shfl_xor(q, 4, 64); q += __shfl_xor(q, 8, 64);
      float rs = rsqrtf(q * (1.f / 192.f) + 1e-5f);
#pragma unroll
      for (int nt = 0; nt < 12; ++nt) v[nt][reg] = (v[nt][reg] - m) * rs;
    }
#pragma unroll
    for (int nt = 0; nt < 12; ++nt) {
      float wv = n2w[nt * 16 + c], bv = n2b[nt * 16 + c];
#pragma unroll
      for (int reg = 0; reg < 4; ++reg) {
        int r = wr + 4 * g + reg;
        int ch = nt * 2 + (c >> 3);
        int ph = (ch & 24) | ((ch ^ (r & 7)) & 7);
        sA[r * 192 + ph * 8 + (c & 7)] = f2b(v[nt][reg] * wv + bv);
      }
    }
  }
  __syncthreads();  // sA visible
  bf16x8 afr[6];
  {
    int ar = wr + c;
#pragma unroll
    for (int ks = 0; ks < 6; ++ks) {
      int ch = ks * 4 + g;
      int ph = (ch & 24) | ((ch ^ (ar & 7)) & 7);
      afr[ks] = *(const bf16x8*)(sA + ar * 192 + ph * 8);
    }
  }
  __syncthreads();  // all afr reads done -> sA region (c1a/c1b) reusable
  stage_frags<12>(w1f, c1a, wave, lane);
  stage_frags<12>(w2f, c2a, wave, lane);
  f32x4 o[12];
#pragma unroll
  for (int i = 0; i < 12; ++i) o[i] = (f32x4){0.f, 0.f, 0.f, 0.f};
  __syncthreads();  // prologue stage drained
  for (int j = 0; j < 24; ++j) {
    int cur = j & 1;
    const u16* r1 = cur ? c1b : c1a;
    const u16* r2 = cur ? c2b : c2a;
    if (j < 23) {
      stage_frags<12>(w1f + (size_t)(j + 1) * 6144, cur ? c1a : c1b, wave, lane);
      stage_frags<12>(w2f + (size_t)(j + 1) * 6144, cur ? c2a : c2b, wave, lane);
    }
    // ---- swapped fc1: S1[ht] = W1_frag x afr -> lane holds P^T[h][m=wr+c] ----
    f32x4 S1[2] = {{0,0,0,0},{0,0,0,0}};
#pragma unroll
    for (int ks = 0; ks < 6; ++ks) {
      bf16x8 w0 = *(const bf16x8*)(r1 + (0 * 6 + ks) * 512 + lane * 8);
      bf16x8 w1v = *(const bf16x8*)(r1 + (1 * 6 + ks) * 512 + lane * 8);
      S1[0] = MFMA16(w0, afr[ks], S1[0]);
      S1[1] = MFMA16(w1v, afr[ks], S1[1]);
    }
    // ---- GELU + lane-local bf16 pack: pf slot (g,i) = h pi(g,i) ----
    union { u16 h[8]; bf16x8 v; } pu;
    float4 bv0 = *(const float4*)(b1 + j * 32 + 4 * g);
    float4 bv1 = *(const float4*)(b1 + j * 32 + 16 + 4 * g);
#pragma unroll
    for (int r = 0; r < 4; ++r) {
      float v0 = S1[0][r] + ((const float*)&bv0)[r];
      float u20 = v0 * (1.5957691216f + 0.0713548163f * v0 * v0);
      pu.h[r] = f2b(v0 / (1.f + __expf(-u20)));
      float v1 = S1[1][r] + ((const float*)&bv1)[r];
      float u21 = v1 * (1.5957691216f + 0.0713548163f * v1 * v1);
      pu.h[r + 4] = f2b(v1 / (1.f + __expf(-u21)));
    }
    // ---- swapped PV: o[ct] += W2_frag(pi-packed) x pf ----
#pragma unroll
    for (int ct = 0; ct < 12; ++ct) {
      bf16x8 wf2 = *(const bf16x8*)(r2 + ct * 512 + lane * 8);
      o[ct] = MFMA16(wf2, pu.v, o[ct]);
    }
    __syncthreads();  // r1/r2 reads done; stage(j+1) drained
  }
  // epilogue: lane holds O^T[cout=ct*16+4g+r][m=wr+c]; residual RMW + bias
  size_t rowoff = (size_t)(m0 + wr + c) * 192;
#pragma unroll
  for (int ct = 0; ct < 12; ++ct) {
    float4 b4 = *(const float4*)(b2 + ct * 16 + 4 * g);
#pragma unroll
    for (int r = 0; r < 4; ++r) {
      size_t oo = rowoff + ct * 16 + 4 * g + r;
      out[oo] = out[oo] + o[ct][r] + ((const float*)&b4)[r];
    }
  }
}

extern "C" void kernel_launch(void* const* d_in, const int* in_sizes, int n_in,
                              void* d_out, int out_size, void* d_ws, size_t ws_size,
                              hipStream_t stream) {
  (void)in_sizes; (void)n_in; (void)out_size;
  const float* x     = (const float*)d_in[0];
  const float* amask = (const float*)d_in[1];
  const float* n1w   = (const float*)d_in[2];
  const float* n1b   = (const float*)d_in[3];
  const float* qkvw  = (const float*)d_in[4];
  const float* qkvb  = (const float*)d_in[5];
  const float* rpb   = (const float*)d_in[6];
  const float* projw = (const float*)d_in[7];
  const float* projb = (const float*)d_in[8];
  const float* n2w   = (const float*)d_in[9];
  const float* n2b   = (const float*)d_in[10];
  const float* fc1w  = (const float*)d_in[11];
  const float* fc1b  = (const float*)d_in[12];
  const float* fc2w  = (const float*)d_in[13];
  const float* fc2b  = (const float*)d_in[14];
  float* out = (float*)d_out;
  char* ws = (char*)d_ws;

  u16* qkvwf = (u16*)(ws);                               // ct-major 36x6
  u16* projwf = (u16*)(ws + 221184);                     // ct-major 12x6
  u16* fc1wf = (u16*)(ws + 221184 + 73728);              // ct-major 48x6
  u16* fc2wf = (u16*)(ws + 221184 + 73728 + 294912);     // pi-packed hs-major 24x12
  char* arena = ws + (1 << 20);
  size_t arena_sz = ws_size > (1 << 20) ? ws_size - (1 << 20) : 0;

  pack_kernel<<<(36 * 6 * 64 + 255) / 256, 256, 0, stream>>>(qkvw, qkvwf, 36, 6, 192, 0);
  pack_kernel<<<(12 * 6 * 64 + 255) / 256, 256, 0, stream>>>(projw, projwf, 12, 6, 192, 0);
  pack_kernel<<<(48 * 6 * 64 + 255) / 256, 256, 0, stream>>>(fc1w, fc1wf, 48, 6, 192, 0);
  pack2_kernel<<<(24 * 12 * 64 + 255) / 256, 256, 0, stream>>>(fc2w, fc2wf);

  // ---- attention path: fused per-window kernel + proj (aout only in ws) ----
  int NCA = 1;
  while (NCA < 16 && (size_t)(2048 / NCA) * 49 * 192 * 2 > arena_sz) NCA <<= 1;
  int Wc = 2048 / NCA;
  for (int cch = 0; cch < NCA; ++cch) {
    int win0 = cch * Wc;
    int tok0 = win0 * 49;
    u16* aout_c = (u16*)arena;
    int rows = Wc * 49;
    attn_win<<<Wc, 256, 0, stream>>>(x, n1w, n1b, qkvwf, qkvb, rpb, amask,
                                     aout_c, win0);
    proj_fused<<<rows / 64, 256, 0, stream>>>(aout_c, projwf, projb, x, out,
                                              tok0);
  }

  // ---- fused MLP: r10-exact (validated 162 us) ----
  mlp_fused<<<1568, 256, 0, stream>>>(n2w, n2b, fc1wf, fc1b, fc2wf, fc2b,
                                      out);
}

// Round 14
// 265.896 us; speedup vs baseline: 1.7118x; 1.2763x over previous
//
#include <hip/hip_runtime.h>
#include <hip/hip_bf16.h>

typedef unsigned short u16;
typedef __attribute__((ext_vector_type(8))) short bf16x8;
typedef __attribute__((ext_vector_type(4))) float f32x4;

#define MFMA16(a, b, c) __builtin_amdgcn_mfma_f32_16x16x32_bf16(a, b, c, 0, 0, 0)

__device__ __forceinline__ u16 f2b(float f) {
  union { float f; unsigned u; } x; x.f = f;
  return (u16)((x.u + 0x7fffu + ((x.u >> 16) & 1u)) >> 16);
}

__device__ __forceinline__ void gload_lds16(const void* g, void* l) {
  __builtin_amdgcn_global_load_lds(
      (const __attribute__((address_space(1))) void*)g,
      (__attribute__((address_space(3))) void*)l, 16, 0, 0);
}

// linear frag-block stage: NCH chunks of 512 u16 (64 lanes x 16B), src contiguous
template <int NCH>
__device__ __forceinline__ void stage_frags(const u16* __restrict__ src,
                                            u16* dst, int wave, int lane) {
#pragma unroll
  for (int it = 0; it < NCH / 4; ++it) {
    int chunk = it * 4 + wave;
    gload_lds16(src + ((size_t)chunk * 64 + lane) * 8, dst + chunk * 512);
  }
}

// stage 64 rows x 192 cols bf16 -> LDS, chunk XOR-swizzled by row&7 (proj A).
__device__ __forceinline__ void stage_64x192(const u16* __restrict__ src,
                                             int stride, u16* dst, int wave,
                                             int lane) {
#pragma unroll
  for (int it = 0; it < 6; ++it) {
    int id = (it * 4 + wave) * 64 + lane;
    int row = id / 24, ph = id - row * 24;
    int lch = (ph & 24) | ((ph ^ (row & 7)) & 7);
    gload_lds16(src + (size_t)row * stride + lch * 8,
                dst + (it * 4 + wave) * 512);
  }
}

// ---------------- weight fp32 -> bf16 MFMA-fragment order ------------------
__global__ __launch_bounds__(256) void pack_kernel(const float* __restrict__ W,
                                                   u16* __restrict__ F, int NT,
                                                   int KS, int K, int kmajor) {
  int f = blockIdx.x * 256 + threadIdx.x;
  if (f >= NT * KS * 64) return;
  int l = f & 63, rest = f >> 6;
  int ks, ct;
  if (kmajor) { ct = rest % NT; ks = rest / NT; }
  else        { ks = rest % KS; ct = rest / KS; }
  int row = ct * 16 + (l & 15);
  int col = ks * 32 + (l >> 4) * 8;
  const float* s = W + (size_t)row * K + col;
  u16* d = F + (size_t)f * 8;
#pragma unroll
  for (int i = 0; i < 8; ++i) d[i] = f2b(s[i]);
}

// fc2 pack with pi-permuted k within each 32-h chunk (matches lane-local pf):
// pi(g,i) = 4g+i (i<4), 16+4g+(i-4) (i>=4). frag id = hs*12 + ct.
__global__ __launch_bounds__(256) void pack2_kernel(const float* __restrict__ W,
                                                    u16* __restrict__ F) {
  int f = blockIdx.x * 256 + threadIdx.x;
  if (f >= 24 * 12 * 64) return;
  int l = f & 63, rest = f >> 6;
  int ct = rest % 12, hs = rest / 12;
  int row = ct * 16 + (l & 15);
  int g = l >> 4;
  u16* d = F + (size_t)f * 8;
#pragma unroll
  for (int i = 0; i < 8; ++i) {
    int h = hs * 32 + (i < 4 ? 4 * g + i : 16 + 4 * g + (i - 4));
    d[i] = f2b(W[(size_t)row * 768 + h]);
  }
}

// ---------------- fused LN1 + shift/window + QKV + attention (v2) ----------
// Swapped-operand qkv: q stays in registers as pi-frag; k one 16B LDS word;
// softmax register-local; P re-packed lane-locally (MLP trick). W via LDS.
__global__ __launch_bounds__(256, 3) void attn_win(
    const float* __restrict__ x, const float* __restrict__ n1w,
    const float* __restrict__ n1b, const u16* __restrict__ qkvwf,
    const float* __restrict__ qkvb_, const float* __restrict__ rpb,
    const float* __restrict__ amask, u16* __restrict__ aout, int win0) {
  __shared__ __align__(16) u16 lds[25088];  // 50,176 B
  u16* wbuf = lds;                // 36 frags (18432 u16); sA overlays
  u16* sA   = lds;                // 64x192 swizzled (12288 u16)
  u16* klds = lds + 18432;        // [64 tok][40] u16 (16B frag words)
  u16* vlds = lds + 21000;        // [32 d][68] u16 (2176) -> ends 23176
  int tid = threadIdx.x, wave = tid >> 6, lane = tid & 63;
  int g = lane >> 4, c = lane & 15, wr = wave * 16;
  int blk = blockIdx.x;
  int wing = win0 + blk;
  int wi = wing & 63;
  // --- LN1 -> sA (rows 49..63 clamp to token 48; masked later) ---
  {
    float vals[12][4];
    int srcrow[4];
#pragma unroll
    for (int reg = 0; reg < 4; ++reg) {
      int n = wr + 4 * g + reg;
      if (n > 48) n = 48;
      int bb = wing >> 6, wloc = wing & 63, wh = wloc >> 3, ww = wloc & 7;
      int rr = n / 7, cc = n - rr * 7;
      int hs = wh * 7 + rr + 3; if (hs >= 56) hs -= 56;
      int wsr = ww * 7 + cc + 3; if (wsr >= 56) wsr -= 56;
      srcrow[reg] = bb * 3136 + hs * 56 + wsr;
    }
#pragma unroll
    for (int nt = 0; nt < 12; ++nt)
#pragma unroll
      for (int reg = 0; reg < 4; ++reg)
        vals[nt][reg] = x[(size_t)srcrow[reg] * 192 + nt * 16 + c];
#pragma unroll
    for (int reg = 0; reg < 4; ++reg) {
      float s = 0.f;
#pragma unroll
      for (int nt = 0; nt < 12; ++nt) s += vals[nt][reg];
      s += __shfl_xor(s, 1, 64); s += __shfl_xor(s, 2, 64);
      s += __shfl_xor(s, 4, 64); s += __shfl_xor(s, 8, 64);
      float m = s * (1.f / 192.f), q = 0.f;
#pragma unroll
      for (int nt = 0; nt < 12; ++nt) { float d = vals[nt][reg] - m; q += d * d; }
      q += __shfl_xor(q, 1, 64); q += __shfl_xor(q, 2, 64);
      q += __shfl_xor(q, 4, 64); q += __shfl_xor(q, 8, 64);
      float rs = rsqrtf(q * (1.f / 192.f) + 1e-5f);
#pragma unroll
      for (int nt = 0; nt < 12; ++nt) vals[nt][reg] = (vals[nt][reg] - m) * rs;
    }
#pragma unroll
    for (int nt = 0; nt < 12; ++nt) {
      float wv = n1w[nt * 16 + c], bv = n1b[nt * 16 + c];
#pragma unroll
      for (int reg = 0; reg < 4; ++reg) {
        int r = wr + 4 * g + reg;
        int ch = nt * 2 + (c >> 3);
        int ph = (ch & 24) | ((ch ^ (r & 7)) & 7);
        sA[r * 192 + ph * 8 + (c & 7)] = f2b(vals[nt][reg] * wv + bv);
      }
    }
  }
  __syncthreads();  // sA visible
  bf16x8 afr[6];
  {
    int ar = wr + c;
#pragma unroll
    for (int ks = 0; ks < 6; ++ks) {
      int ch = ks * 4 + g;
      int ph = (ch & 24) | ((ch ^ (ar & 7)) & 7);
      afr[ks] = *(const bf16x8*)(sA + ar * 192 + ph * 8);
    }
  }
  __syncthreads();  // sA dead everywhere -> wbuf region usable
  // stage W[0] (3 groups of 12 contiguous frags)
#pragma unroll
  for (int s = 0; s < 3; ++s)
    stage_frags<12>(qkvwf + (size_t)((s * 12 + 0) * 6) * 512, wbuf + s * 6144,
                    wave, lane);
  // hoist mask + rel-pos index (fixed across heads)
  int nq = wr + c;            // this thread's query token
  int nb = nq > 48 ? 48 : nq;
  int ridx[16];
  float pm[16];
  {
    int i1 = nb / 7, j1 = nb - i1 * 7;
#pragma unroll
    for (int kt = 0; kt < 4; ++kt)
#pragma unroll
      for (int reg = 0; reg < 4; ++reg) {
        int m = kt * 16 + 4 * g + reg;
        int idx = kt * 4 + reg;
        if (m < 49) {
          int i2 = m / 7, j2 = m - i2 * 7;
          ridx[idx] = ((i1 - i2 + 6) * 13 + (j1 - j2 + 6)) * 6;
          pm[idx] = amask[(size_t)wi * 2401 + nb * 49 + m];
        } else {
          ridx[idx] = 0;
          pm[idx] = -1e30f;
        }
      }
  }
  __syncthreads();  // W[0] staged (barrier drains vmcnt)
  for (int h = 0; h < 6; ++h) {
    // ---- swapped qkv: thread gets q/k/v of token nq at d = pi(g,i) ----
    f32x4 qa[2], ka[2], va[2];
#pragma unroll
    for (int s = 0; s < 3; ++s)
#pragma unroll
      for (int t = 0; t < 2; ++t) {
        f32x4 acc = {0.f, 0.f, 0.f, 0.f};
#pragma unroll
        for (int ks = 0; ks < 6; ++ks) {
          bf16x8 wf = *(const bf16x8*)(wbuf + (s * 12 + t * 6 + ks) * 512 +
                                       lane * 8);
          acc = MFMA16(wf, afr[ks], acc);
        }
        float4 b4 = *(const float4*)(qkvb_ + s * 192 + h * 32 + t * 16 + 4 * g);
#pragma unroll
        for (int reg = 0; reg < 4; ++reg) acc[reg] += ((const float*)&b4)[reg];
        if (s == 0) qa[t] = acc;
        else if (s == 1) ka[t] = acc;
        else va[t] = acc;
      }
    // q -> register pi-frag; k -> one 16B LDS word; v -> [d][m] tile
    union { u16 hh[8]; bf16x8 v; } qf, kf;
#pragma unroll
    for (int reg = 0; reg < 4; ++reg) {
      qf.hh[reg] = f2b(qa[0][reg]);
      qf.hh[reg + 4] = f2b(qa[1][reg]);
      kf.hh[reg] = f2b(ka[0][reg]);
      kf.hh[reg + 4] = f2b(ka[1][reg]);
    }
    *(bf16x8*)(klds + nq * 40 + g * 8) = kf.v;
#pragma unroll
    for (int t = 0; t < 2; ++t)
#pragma unroll
      for (int reg = 0; reg < 4; ++reg)
        vlds[(t * 16 + 4 * g + reg) * 68 + nq] = f2b(va[t][reg]);
    __syncthreads();  // k/v visible; all wbuf reads done
    if (h < 5) {
#pragma unroll
      for (int s = 0; s < 3; ++s)
        stage_frags<12>(qkvwf + (size_t)((s * 12 + (h + 1) * 2) * 6) * 512,
                        wbuf + s * 6144, wave, lane);
    }
    // ---- S = MFMA(k_frag, q_frag): thread holds S[m=kt*16+4g+reg][n=nq] ----
    float sv[16];
#pragma unroll
    for (int kt = 0; kt < 4; ++kt) {
      bf16x8 kw = *(const bf16x8*)(klds + (kt * 16 + c) * 40 + g * 8);
      f32x4 z = {0.f, 0.f, 0.f, 0.f};
      f32x4 sacc = MFMA16(kw, qf.v, z);
#pragma unroll
      for (int reg = 0; reg < 4; ++reg) sv[kt * 4 + reg] = sacc[reg];
    }
    // ---- softmax (register-local; reduce across g-groups) ----
    const float scale = 0.17677669529663687f;
    float mx = -1e30f;
#pragma unroll
    for (int i = 0; i < 16; ++i) {
      sv[i] = sv[i] * scale + rpb[ridx[i] + h] + pm[i];
      mx = fmaxf(mx, sv[i]);
    }
    mx = fmaxf(mx, __shfl_xor(mx, 16, 64));
    mx = fmaxf(mx, __shfl_xor(mx, 32, 64));
    float se = 0.f;
#pragma unroll
    for (int i = 0; i < 16; ++i) {
      sv[i] = __expf(sv[i] - mx);
      se += sv[i];
    }
    se += __shfl_xor(se, 16, 64);
    se += __shfl_xor(se, 32, 64);
    float inv = 1.0f / se;
    // pack P into 2 pi-frags (slot i<4: kt=2*mblk, reg=i; i>=4: kt=2*mblk+1)
    union { u16 hh[8]; bf16x8 v; } pu0, pu1;
#pragma unroll
    for (int reg = 0; reg < 4; ++reg) {
      pu0.hh[reg] = f2b(sv[0 * 4 + reg] * inv);
      pu0.hh[reg + 4] = f2b(sv[1 * 4 + reg] * inv);
      pu1.hh[reg] = f2b(sv[2 * 4 + reg] * inv);
      pu1.hh[reg + 4] = f2b(sv[3 * 4 + reg] * inv);
    }
    // ---- PV: O^T[d][n] += V^T_frag x P_frag ----
    f32x4 oacc[2] = {{0, 0, 0, 0}, {0, 0, 0, 0}};
#pragma unroll
    for (int nt = 0; nt < 2; ++nt)
#pragma unroll
      for (int mblk = 0; mblk < 2; ++mblk) {
        const u16* vp = vlds + (nt * 16 + c) * 68 + mblk * 32 + 4 * g;
        union { u16 hh[8]; bf16x8 v; } vt;
        *(short4*)(vt.hh) = *(const short4*)(vp);
        *(short4*)(vt.hh + 4) = *(const short4*)(vp + 16);
        oacc[nt] = MFMA16(vt.v, mblk ? pu1.v : pu0.v, oacc[nt]);
      }
    if (nq < 49) {
      u16* op = aout + ((size_t)blk * 49 + nq) * 192 + h * 32;
#pragma unroll
      for (int nt = 0; nt < 2; ++nt) {
        ushort4 st;
        st.x = f2b(oacc[nt][0]);
        st.y = f2b(oacc[nt][1]);
        st.z = f2b(oacc[nt][2]);
        st.w = f2b(oacc[nt][3]);
        *(ushort4*)(op + nt * 16 + 4 * g) = st;
      }
    }
    __syncthreads();  // klds/vlds reads done; W[h+1] stage drained
  }
}

// ---------------- fused proj + window reverse + unshift + residual ---------
__global__ __launch_bounds__(256, 3) void proj_fused(
    const u16* __restrict__ aout, const u16* __restrict__ wf,
    const float* __restrict__ pb, const float* __restrict__ x,
    float* __restrict__ out, int tok0) {
  __shared__ __align__(16) u16 lds[24576];  // 48 KB
  u16* sA = lds;
  u16* b0 = lds;
  u16* b1 = lds + 12288;
  int tid = threadIdx.x, wave = tid >> 6, lane = tid & 63;
  int g = lane >> 4, c = lane & 15;
  int m0 = blockIdx.x * 64;
  stage_64x192(aout + (size_t)m0 * 192, 192, sA, wave, lane);
  asm volatile("s_waitcnt vmcnt(0)" ::: "memory");
  __syncthreads();
  int mw = wave >> 1, nw = wave & 1;
  bf16x8 afr[2][6];
#pragma unroll
  for (int rt = 0; rt < 2; ++rt) {
    int ar = mw * 32 + rt * 16 + c;
#pragma unroll
    for (int ks = 0; ks < 6; ++ks) {
      int ch = ks * 4 + g;
      int ph = (ch & 24) | ((ch ^ (ar & 7)) & 7);
      afr[rt][ks] = *(const bf16x8*)(sA + ar * 192 + ph * 8);
    }
  }
  size_t trow[2][4];
#pragma unroll
  for (int rt = 0; rt < 2; ++rt)
#pragma unroll
    for (int reg = 0; reg < 4; ++reg) {
      int rg = tok0 + m0 + mw * 32 + rt * 16 + 4 * g + reg;
      int win = rg / 49, n = rg - win * 49;
      int b_ = win >> 6, wi = win & 63;
      int wh = wi >> 3, ww = wi & 7;
      int rr = n / 7, cc = n - rr * 7;
      int hd_ = wh * 7 + rr + 3; if (hd_ >= 56) hd_ -= 56;
      int wd = ww * 7 + cc + 3; if (wd >= 56) wd -= 56;
      trow[rt][reg] = (size_t)b_ * 3136 + hd_ * 56 + wd;
    }
  __syncthreads();  // afr reads done -> sA region (b0) reusable
  stage_frags<24>(wf, b0, wave, lane);
  __syncthreads();  // b0 staged
  for (int j = 0; j < 3; ++j) {
    const u16* cb = (j & 1) ? b1 : b0;
    if (j < 2)
      stage_frags<24>(wf + (size_t)(j + 1) * 24 * 512, (j & 1) ? b0 : b1, wave,
                      lane);
    f32x4 S[2][2] = {{{0,0,0,0},{0,0,0,0}},{{0,0,0,0},{0,0,0,0}}};
#pragma unroll
    for (int nt = 0; nt < 2; ++nt)
#pragma unroll
      for (int ks = 0; ks < 6; ++ks) {
        bf16x8 bf = *(const bf16x8*)(cb + ((nw * 2 + nt) * 6 + ks) * 512 + lane * 8);
        S[0][nt] = MFMA16(afr[0][ks], bf, S[0][nt]);
        S[1][nt] = MFMA16(afr[1][ks], bf, S[1][nt]);
      }
#pragma unroll
    for (int nt = 0; nt < 2; ++nt) {
      int jc = j * 64 + nw * 32 + nt * 16 + c;
      float bv = pb[jc];
#pragma unroll
      for (int rt = 0; rt < 2; ++rt)
#pragma unroll
        for (int reg = 0; reg < 4; ++reg) {
          size_t o = trow[rt][reg] * 192 + jc;
          out[o] = x[o] + S[rt][nt][reg] + bv;
        }
    }
    __syncthreads();
  }
}

// ---------------- fused LN2 + fc1 + GELU + fc2 + residual (r10 exact) ------
__global__ __launch_bounds__(256, 3) void mlp_fused(
    const float* __restrict__ n2w, const float* __restrict__ n2b,
    const u16* __restrict__ w1f, const float* __restrict__ b1,
    const u16* __restrict__ w2f, const float* __restrict__ b2,
    float* __restrict__ out) {
  __shared__ __align__(16) u16 lds[24576];  // 48 KB
  u16* c1a = lds;            // 12 frags (6144 u16) fc1 buf0
  u16* c1b = lds + 6144;
  u16* c2a = lds + 12288;    // fc2 buf0
  u16* c2b = lds + 18432;
  u16* sA  = lds;            // 64x192 overlay (c1a+c1b), dead after afr loads
  int tid = threadIdx.x, wave = tid >> 6, lane = tid & 63;
  int g = lane >> 4, c = lane & 15, wr = wave * 16;
  int m0 = blockIdx.x * 64;
  // --- LN2: wave owns 16 rows -> sA swizzled ---
  {
    float v[12][4];
    int rr[4];
#pragma unroll
    for (int reg = 0; reg < 4; ++reg) rr[reg] = m0 + wr + 4 * g + reg;
#pragma unroll
    for (int nt = 0; nt < 12; ++nt)
#pragma unroll
      for (int reg = 0; reg < 4; ++reg)
        v[nt][reg] = out[(size_t)rr[reg] * 192 + nt * 16 + c];
#pragma unroll
    for (int reg = 0; reg < 4; ++reg) {
      float s = 0.f;
#pragma unroll
      for (int nt = 0; nt < 12; ++nt) s += v[nt][reg];
      s += __shfl_xor(s, 1, 64); s += __shfl_xor(s, 2, 64);
      s += __shfl_xor(s, 4, 64); s += __shfl_xor(s, 8, 64);
      float m = s * (1.f / 192.f), q = 0.f;
#pragma unroll
      for (int nt = 0; nt < 12; ++nt) { float d = v[nt][reg] - m; q += d * d; }
      q += __shfl_xor(q, 1, 64); q += __shfl_xor(q, 2, 64);
      q += __shfl_xor(q, 4, 64); q += __shfl_xor(q, 8, 64);
      float rs = rsqrtf(q * (1.f / 192.f) + 1e-5f);
#pragma unroll
      for (int nt = 0; nt < 12; ++nt) v[nt][reg] = (v[nt][reg] - m) * rs;
    }
#pragma unroll
    for (int nt = 0; nt < 12; ++nt) {
      float wv = n2w[nt * 16 + c], bv = n2b[nt * 16 + c];
#pragma unroll
      for (int reg = 0; reg < 4; ++reg) {
        int r = wr + 4 * g + reg;
        int ch = nt * 2 + (c >> 3);
        int ph = (ch & 24) | ((ch ^ (r & 7)) & 7);
        sA[r * 192 + ph * 8 + (c & 7)] = f2b(v[nt][reg] * wv + bv);
      }
    }
  }
  __syncthreads();  // sA visible
  bf16x8 afr[6];
  {
    int ar = wr + c;
#pragma unroll
    for (int ks = 0; ks < 6; ++ks) {
      int ch = ks * 4 + g;
      int ph = (ch & 24) | ((ch ^ (ar & 7)) & 7);
      afr[ks] = *(const bf16x8*)(sA + ar * 192 + ph * 8);
    }
  }
  __syncthreads();  // all afr reads done -> sA region (c1a/c1b) reusable
  stage_frags<12>(w1f, c1a, wave, lane);
  stage_frags<12>(w2f, c2a, wave, lane);
  f32x4 o[12];
#pragma unroll
  for (int i = 0; i < 12; ++i) o[i] = (f32x4){0.f, 0.f, 0.f, 0.f};
  __syncthreads();  // prologue stage drained
  for (int j = 0; j < 24; ++j) {
    int cur = j & 1;
    const u16* r1 = cur ? c1b : c1a;
    const u16* r2 = cur ? c2b : c2a;
    if (j < 23) {
      stage_frags<12>(w1f + (size_t)(j + 1) * 6144, cur ? c1a : c1b, wave, lane);
      stage_frags<12>(w2f + (size_t)(j + 1) * 6144, cur ? c2a : c2b, wave, lane);
    }
    // ---- swapped fc1: S1[ht] = W1_frag x afr -> lane holds P^T[h][m=wr+c] ----
    f32x4 S1[2] = {{0,0,0,0},{0,0,0,0}};
#pragma unroll
    for (int ks = 0; ks < 6; ++ks) {
      bf16x8 w0 = *(const bf16x8*)(r1 + (0 * 6 + ks) * 512 + lane * 8);
      bf16x8 w1v = *(const bf16x8*)(r1 + (1 * 6 + ks) * 512 + lane * 8);
      S1[0] = MFMA16(w0, afr[ks], S1[0]);
      S1[1] = MFMA16(w1v, afr[ks], S1[1]);
    }
    // ---- GELU + lane-local bf16 pack: pf slot (g,i) = h pi(g,i) ----
    union { u16 h[8]; bf16x8 v; } pu;
    float4 bv0 = *(const float4*)(b1 + j * 32 + 4 * g);
    float4 bv1 = *(const float4*)(b1 + j * 32 + 16 + 4 * g);
#pragma unroll
    for (int r = 0; r < 4; ++r) {
      float v0 = S1[0][r] + ((const float*)&bv0)[r];
      float u20 = v0 * (1.5957691216f + 0.0713548163f * v0 * v0);
      pu.h[r] = f2b(v0 / (1.f + __expf(-u20)));
      float v1 = S1[1][r] + ((const float*)&bv1)[r];
      float u21 = v1 * (1.5957691216f + 0.0713548163f * v1 * v1);
      pu.h[r + 4] = f2b(v1 / (1.f + __expf(-u21)));
    }
    // ---- swapped PV: o[ct] += W2_frag(pi-packed) x pf ----
#pragma unroll
    for (int ct = 0; ct < 12; ++ct) {
      bf16x8 wf2 = *(const bf16x8*)(r2 + ct * 512 + lane * 8);
      o[ct] = MFMA16(wf2, pu.v, o[ct]);
    }
    __syncthreads();  // r1/r2 reads done; stage(j+1) drained
  }
  // epilogue: lane holds O^T[cout=ct*16+4g+r][m=wr+c]; residual RMW + bias
  size_t rowoff = (size_t)(m0 + wr + c) * 192;
#pragma unroll
  for (int ct = 0; ct < 12; ++ct) {
    float4 b4 = *(const float4*)(b2 + ct * 16 + 4 * g);
#pragma unroll
    for (int r = 0; r < 4; ++r) {
      size_t oo = rowoff + ct * 16 + 4 * g + r;
      out[oo] = out[oo] + o[ct][r] + ((const float*)&b4)[r];
    }
  }
}

extern "C" void kernel_launch(void* const* d_in, const int* in_sizes, int n_in,
                              void* d_out, int out_size, void* d_ws, size_t ws_size,
                              hipStream_t stream) {
  (void)in_sizes; (void)n_in; (void)out_size;
  const float* x     = (const float*)d_in[0];
  const float* amask = (const float*)d_in[1];
  const float* n1w   = (const float*)d_in[2];
  const float* n1b   = (const float*)d_in[3];
  const float* qkvw  = (const float*)d_in[4];
  const float* qkvb  = (const float*)d_in[5];
  const float* rpb   = (const float*)d_in[6];
  const float* projw = (const float*)d_in[7];
  const float* projb = (const float*)d_in[8];
  const float* n2w   = (const float*)d_in[9];
  const float* n2b   = (const float*)d_in[10];
  const float* fc1w  = (const float*)d_in[11];
  const float* fc1b  = (const float*)d_in[12];
  const float* fc2w  = (const float*)d_in[13];
  const float* fc2b  = (const float*)d_in[14];
  float* out = (float*)d_out;
  char* ws = (char*)d_ws;

  u16* qkvwf = (u16*)(ws);                               // ct-major 36x6
  u16* projwf = (u16*)(ws + 221184);                     // ct-major 12x6
  u16* fc1wf = (u16*)(ws + 221184 + 73728);              // ct-major 48x6
  u16* fc2wf = (u16*)(ws + 221184 + 73728 + 294912);     // pi-packed hs-major 24x12
  char* arena = ws + (1 << 20);
  size_t arena_sz = ws_size > (1 << 20) ? ws_size - (1 << 20) : 0;

  pack_kernel<<<(36 * 6 * 64 + 255) / 256, 256, 0, stream>>>(qkvw, qkvwf, 36, 6, 192, 0);
  pack_kernel<<<(12 * 6 * 64 + 255) / 256, 256, 0, stream>>>(projw, projwf, 12, 6, 192, 0);
  pack_kernel<<<(48 * 6 * 64 + 255) / 256, 256, 0, stream>>>(fc1w, fc1wf, 48, 6, 192, 0);
  pack2_kernel<<<(24 * 12 * 64 + 255) / 256, 256, 0, stream>>>(fc2w, fc2wf);

  // ---- attention path: fused per-window kernel + proj (aout only in ws) ----
  int NCA = 1;
  while (NCA < 16 && (size_t)(2048 / NCA) * 49 * 192 * 2 > arena_sz) NCA <<= 1;
  int Wc = 2048 / NCA;
  for (int cch = 0; cch < NCA; ++cch) {
    int win0 = cch * Wc;
    int tok0 = win0 * 49;
    u16* aout_c = (u16*)arena;
    int rows = Wc * 49;
    attn_win<<<Wc, 256, 0, stream>>>(x, n1w, n1b, qkvwf, qkvb, rpb, amask,
                                     aout_c, win0);
    proj_fused<<<rows / 64, 256, 0, stream>>>(aout_c, projwf, projb, x, out,
                                              tok0);
  }

  // ---- fused MLP: r10-exact (validated 162 us) ----
  mlp_fused<<<1568, 256, 0, stream>>>(n2w, n2b, fc1wf, fc1b, fc2wf, fc2b,
                                      out);
}